// Round 1
// baseline (1227.073 us; speedup 1.0000x reference)
//
#include <hip/hip_runtime.h>
#include <hip/hip_fp16.h>

typedef _Float16 f16;
typedef _Float16 f16x2 __attribute__((ext_vector_type(2)));
typedef _Float16 f16x4 __attribute__((ext_vector_type(4)));
typedef _Float16 f16x8 __attribute__((ext_vector_type(8)));
typedef float    f32x4 __attribute__((ext_vector_type(4)));

#define DEV __device__ __forceinline__

constexpr int B = 32, T = 64, S = 64, H = 512, E = 512, V = 32000;
constexpr int BT = B * T;      // 2048
constexpr int G4 = 4 * H;      // 2048

#if defined(__has_builtin)
#if __has_builtin(__builtin_amdgcn_fdot2)
#define HAVE_FDOT2 1
#endif
#endif

DEV float dot2(unsigned int a, unsigned int b, float c) {
#if HAVE_FDOT2
    return __builtin_amdgcn_fdot2(__builtin_bit_cast(f16x2, a),
                                  __builtin_bit_cast(f16x2, b), c, false);
#else
    f16x2 av = __builtin_bit_cast(f16x2, a);
    f16x2 bv = __builtin_bit_cast(f16x2, b);
    return c + (float)av.x * (float)bv.x + (float)av.y * (float)bv.y;
#endif
}

DEV float sigf(float x) { return 1.f / (1.f + expf(-x)); }

// ---------------- converts / packing ----------------

__global__ __launch_bounds__(256) void cvt_f16(const float* __restrict__ s,
                                               f16* __restrict__ d, int n4) {
    for (int i = blockIdx.x * blockDim.x + threadIdx.x; i < n4;
         i += gridDim.x * blockDim.x) {
        float4 v = ((const float4*)s)[i];
        f16x4 o = {(f16)v.x, (f16)v.y, (f16)v.z, (f16)v.w};
        ((f16x4*)d)[i] = o;
    }
}

DEV unsigned int pkh2(float a, float b) {
    f16x2 h = {(f16)a, (f16)b};
    return __builtin_bit_cast(unsigned int, h);
}

// W_hh [2048][512] f32 -> tw4 [256][512] uint4:
// tw4[k2][j] = {half2(W[j][2k2],W[j][2k2+1]), same for rows 512+j, 1024+j, 1536+j}
__global__ __launch_bounds__(256) void pack_whh(const float* __restrict__ W,
                                                uint4* __restrict__ tw4) {
    int id = blockIdx.x * blockDim.x + threadIdx.x;
    if (id >= 256 * 512) return;
    int k2 = id >> 9;
    int j = id & 511;
    float2 a = *(const float2*)(W + (size_t)j * 512 + 2 * k2);
    float2 f = *(const float2*)(W + (size_t)(512 + j) * 512 + 2 * k2);
    float2 g = *(const float2*)(W + (size_t)(1024 + j) * 512 + 2 * k2);
    float2 o = *(const float2*)(W + (size_t)(1536 + j) * 512 + 2 * k2);
    uint4 v;
    v.x = pkh2(a.x, a.y);
    v.y = pkh2(f.x, f.y);
    v.z = pkh2(g.x, g.y);
    v.w = pkh2(o.x, o.y);
    tw4[id] = v;
}

// x[bt][e] = (f16) emb[tok[bt]][e]
__global__ __launch_bounds__(256) void gather_x(const int* __restrict__ tok,
                                                const float* __restrict__ emb,
                                                f16* __restrict__ x) {
    int id = blockIdx.x * blockDim.x + threadIdx.x;  // 2048*128
    if (id >= BT * (E / 4)) return;
    int row = id >> 7;
    int e4 = (id & 127) * 4;
    int t = tok[row];
    float4 v = *(const float4*)(emb + (size_t)t * E + e4);
    f16x4 o = {(f16)v.x, (f16)v.y, (f16)v.z, (f16)v.w};
    ((f16x4*)x)[id] = o;
}

// ---------------- GEMM: C[M,N] = A[M,K] @ W[N,K]^T (+bias, +tanh) ----------------
// 128x128 tile, BK=32, 256 threads = 4 waves (2x2 of 64x64),
// mfma_f32_16x16x32_f16, reg-staged LDS.

template <bool BIAS, bool B2, bool TANH, typename OUT>
__global__ __launch_bounds__(256) void gemm_bt(
    const f16* __restrict__ A, int lda, const f16* __restrict__ W, int ldw,
    OUT* __restrict__ C, int ldc, int K, const float* __restrict__ bias1,
    const float* __restrict__ bias2) {
    __shared__ f16 smA[128 * 32];
    __shared__ f16 smB[128 * 32];
    const int tid = threadIdx.x;
    const int lane = tid & 63;
    const int wv = tid >> 6;
    const int wr = wv >> 1, wc = wv & 1;
    const int m0 = blockIdx.y * 128, n0 = blockIdx.x * 128;

    const int ar0 = tid >> 2;        // staging row 0..63 (and +64)
    const int kq = (tid & 3) * 8;    // half-offset within BK=32

    f32x4 acc[4][4];
#pragma unroll
    for (int m = 0; m < 4; m++)
#pragma unroll
        for (int n = 0; n < 4; n++) acc[m][n] = {0.f, 0.f, 0.f, 0.f};

    const int arow = wr * 64 + (lane & 15);
    const int brow = wc * 64 + (lane & 15);
    const int kk = (lane >> 4) * 8;

    const int ksteps = K >> 5;
    for (int s = 0; s < ksteps; ++s) {
        const int k0 = s * 32;
        const f16* Ag = A + (size_t)(m0 + ar0) * lda + k0 + kq;
        const f16* Wg = W + (size_t)(n0 + ar0) * ldw + k0 + kq;
        uint4 va0 = *(const uint4*)Ag;
        uint4 va1 = *(const uint4*)(Ag + (size_t)64 * lda);
        uint4 vb0 = *(const uint4*)Wg;
        uint4 vb1 = *(const uint4*)(Wg + (size_t)64 * ldw);
        __syncthreads();  // previous compute done -> LDS free
        *(uint4*)(smA + tid * 8) = va0;
        *(uint4*)(smA + (tid + 256) * 8) = va1;
        *(uint4*)(smB + tid * 8) = vb0;
        *(uint4*)(smB + (tid + 256) * 8) = vb1;
        __syncthreads();  // LDS ready
        f16x8 af[4], bf[4];
#pragma unroll
        for (int m = 0; m < 4; m++)
            af[m] = *(const f16x8*)(smA + (arow + m * 16) * 32 + kk);
#pragma unroll
        for (int n = 0; n < 4; n++)
            bf[n] = *(const f16x8*)(smB + (brow + n * 16) * 32 + kk);
#pragma unroll
        for (int m = 0; m < 4; m++)
#pragma unroll
            for (int n = 0; n < 4; n++)
                acc[m][n] = __builtin_amdgcn_mfma_f32_16x16x32_f16(
                    af[m], bf[n], acc[m][n], 0, 0, 0);
    }

    const int fr = lane & 15, fq = lane >> 4;
#pragma unroll
    for (int m = 0; m < 4; m++) {
        const int row0 = m0 + wr * 64 + m * 16 + fq * 4;
#pragma unroll
        for (int n = 0; n < 4; n++) {
            const int col = n0 + wc * 64 + n * 16 + fr;
            float bb = 0.f;
            if (BIAS) bb += bias1[col];
            if (B2) bb += bias2[col];
#pragma unroll
            for (int r = 0; r < 4; r++) {
                float v = acc[m][n][r] + bb;
                if (TANH) v = tanhf(v);
                C[(size_t)(row0 + r) * ldc + col] = (OUT)v;
            }
        }
    }
}

// ---------------- sequential LSTM scan: 1 block per batch ----------------
// gates_x fp32 [B][T][2048]; tw4 uint4 [256][512]; writes h (f16) into
// merged[bt][0:512]; final h,c fp32 to out tail.

__global__ __launch_bounds__(512) void lstm_scan(
    const float* __restrict__ gx, const uint4* __restrict__ tw4,
    const float* __restrict__ h0, const float* __restrict__ c0,
    f16* __restrict__ merged, float* __restrict__ hout,
    float* __restrict__ cout) {
    const int b = blockIdx.x;
    const int j = threadIdx.x;
    __shared__ unsigned int hbuf[2][256];  // h as half2-packed, double buffered

    float c = c0[b * H + j];
    ((f16*)hbuf[0])[j] = (f16)h0[b * H + j];
    __syncthreads();

    const float* gxb = gx + (size_t)b * T * G4;
    const uint4* twp = tw4 + j;
    float h = 0.f;

    for (int t = 0; t < T; ++t) {
        const unsigned int* hp = hbuf[t & 1];
        float ai = gxb[t * G4 + j];
        float af = gxb[t * G4 + 512 + j];
        float ag = gxb[t * G4 + 1024 + j];
        float ao = gxb[t * G4 + 1536 + j];
#pragma unroll 4
        for (int k2 = 0; k2 < 256; ++k2) {
            unsigned int hh = hp[k2];
            uint4 w = twp[(size_t)k2 * 512];
            ai = dot2(hh, w.x, ai);
            af = dot2(hh, w.y, af);
            ag = dot2(hh, w.z, ag);
            ao = dot2(hh, w.w, ao);
        }
        c = sigf(af) * c + sigf(ai) * tanhf(ag);
        h = sigf(ao) * tanhf(c);
        ((f16*)hbuf[(t & 1) ^ 1])[j] = (f16)h;
        merged[(size_t)(b * T + t) * 1536 + j] = (f16)h;
        __syncthreads();
    }
    hout[b * H + j] = h;
    cout[b * H + j] = c;
}

// ---------------- fused attention: w = q.enc ; applied = w.enc ----------------
// one block (256 thr) per (b,t); writes applied (f16) into merged[bt][512:1536]

__global__ __launch_bounds__(256) void attn_apply(const float* __restrict__ q,
                                                  const float* __restrict__ enc,
                                                  f16* __restrict__ merged) {
    const int bt = blockIdx.x;
    const int b = bt >> 6;
    const int tid = threadIdx.x;
    __shared__ float qs[1024];
    __shared__ float ws[64];

    const float* qrow = q + (size_t)bt * 1024;
    *(float4*)(qs + tid * 4) = *(const float4*)(qrow + tid * 4);
    __syncthreads();

    const int wv = tid >> 6, lane = tid & 63;
    const float* encb = enc + (size_t)b * S * 1024;
    for (int s = wv * 16; s < wv * 16 + 16; ++s) {
        const float* er = encb + (size_t)s * 1024;
        float p = 0.f;
#pragma unroll
        for (int i = 0; i < 16; ++i) p += qs[lane + 64 * i] * er[lane + 64 * i];
#pragma unroll
        for (int off = 32; off; off >>= 1) p += __shfl_xor(p, off);
        if (lane == 0) ws[s] = p;
    }
    __syncthreads();

    float a0 = 0.f, a1 = 0.f, a2 = 0.f, a3 = 0.f;
    for (int s = 0; s < 64; ++s) {
        float w = ws[s];
        const float* er = encb + (size_t)s * 1024;
        a0 += w * er[tid];
        a1 += w * er[tid + 256];
        a2 += w * er[tid + 512];
        a3 += w * er[tid + 768];
    }
    f16* mrow = merged + (size_t)bt * 1536 + 512;
    mrow[tid] = (f16)a0;
    mrow[tid + 256] = (f16)a1;
    mrow[tid + 512] = (f16)a2;
    mrow[tid + 768] = (f16)a3;
}

// ---------------- launcher ----------------

extern "C" void kernel_launch(void* const* d_in, const int* in_sizes, int n_in,
                              void* d_out, int out_size, void* d_ws,
                              size_t ws_size, hipStream_t stream) {
    const int* tok = (const int*)d_in[0];
    const float* enc = (const float*)d_in[1];
    const float* h0 = (const float*)d_in[2];
    const float* c0 = (const float*)d_in[3];
    const float* emb = (const float*)d_in[4];
    const float* W_ih = (const float*)d_in[5];
    const float* W_hh = (const float*)d_in[6];
    const float* b_ih = (const float*)d_in[7];
    const float* b_hh = (const float*)d_in[8];
    const float* W_att = (const float*)d_in[9];
    const float* W_comb = (const float*)d_in[10];
    const float* b_comb = (const float*)d_in[11];
    const float* W_out = (const float*)d_in[12];
    const float* b_out = (const float*)d_in[13];

    float* out_logits = (float*)d_out;
    float* out_h = out_logits + (size_t)BT * V;
    float* out_c = out_h + (size_t)B * H;

    char* p = (char*)d_ws;
    auto alloc = [&](size_t bytes) -> void* {
        void* r = (void*)p;
        p += (bytes + 255) & ~(size_t)255;
        return r;
    };
    f16* W_ih_h = (f16*)alloc((size_t)G4 * E * 2);
    uint4* tw4 = (uint4*)alloc((size_t)256 * 512 * 16);
    f16* W_att_h = (f16*)alloc((size_t)1024 * 512 * 2);
    f16* W_comb_h = (f16*)alloc((size_t)512 * 1536 * 2);
    f16* W_out_h = (f16*)alloc((size_t)V * 512 * 2);
    f16* x_h = (f16*)alloc((size_t)BT * E * 2);
    float* gatesx = (float*)alloc((size_t)BT * G4 * 4);
    f16* merged = (f16*)alloc((size_t)BT * 1536 * 2);
    float* qbuf = (float*)alloc((size_t)BT * 1024 * 4);
    f16* outs_h = (f16*)alloc((size_t)BT * 512 * 2);

    cvt_f16<<<512, 256, 0, stream>>>(W_ih, W_ih_h, G4 * E / 4);
    cvt_f16<<<512, 256, 0, stream>>>(W_att, W_att_h, 1024 * 512 / 4);
    cvt_f16<<<512, 256, 0, stream>>>(W_comb, W_comb_h, 512 * 1536 / 4);
    cvt_f16<<<2048, 256, 0, stream>>>(W_out, W_out_h, V * 512 / 4);
    pack_whh<<<512, 256, 0, stream>>>(W_hh, tw4);
    gather_x<<<1024, 256, 0, stream>>>(tok, emb, x_h);

    // gates_x = x @ W_ih^T + b_ih + b_hh   [2048 x 2048]
    gemm_bt<true, true, false, float><<<dim3(16, 16), 256, 0, stream>>>(
        x_h, E, W_ih_h, E, gatesx, G4, E, b_ih, b_hh);

    // sequential LSTM
    lstm_scan<<<32, 512, 0, stream>>>(gatesx, tw4, h0, c0, merged, out_h,
                                      out_c);

    // q = h_all @ W_att^T   [2048 x 1024]  (A = merged cols 0:512, lda=1536)
    gemm_bt<false, false, false, float><<<dim3(8, 16), 256, 0, stream>>>(
        merged, 1536, W_att_h, 512, qbuf, 1024, 512, nullptr, nullptr);

    // attention -> merged[:,512:1536]
    attn_apply<<<BT, 256, 0, stream>>>(qbuf, enc, merged);

    // outs = tanh(merged @ W_comb^T + b_comb)   [2048 x 512] f16
    gemm_bt<true, false, true, f16><<<dim3(4, 16), 256, 0, stream>>>(
        merged, 1536, W_comb_h, 1536, outs_h, 512, 1536, b_comb, nullptr);

    // logits = outs @ W_out^T + b_out   [2048 x 32000] fp32 -> d_out
    gemm_bt<true, false, false, float><<<dim3(250, 16), 256, 0, stream>>>(
        outs_h, 512, W_out_h, 512, out_logits, V, 512, b_out, nullptr);
}